// Round 8
// baseline (366.408 us; speedup 1.0000x reference)
//
#include <hip/hip_runtime.h>
#include <hip/hip_bf16.h>

#define DEVFN static __device__ __forceinline__

typedef short bf16x8 __attribute__((ext_vector_type(8)));
typedef float f32x4  __attribute__((ext_vector_type(4)));

// ---------------- problem constants ----------------
constexpr int TSEQ  = 79;
constexpr int NSTEP = TSEQ + 7;    // 86 wavefront steps (even -> unroll by 2)
constexpr int MWG   = 16;          // batch rows per workgroup
constexpr int ROWU  = 344;         // LDS row stride in bf16 (172 dwords, %32==12 -> uniform banks)
constexpr int NBLK  = 16384 / MWG; // 1024 blocks = 4 blocks/CU (512 thr -> 8 waves/SIMD)

// per-layer tables. Unit map: x at unit 0; layer l h at [LO[l], LO[l]+LU[l]).
constexpr int LD[8]   = {1,64,32,16,8,16,32,64};        // input dim
constexpr int LU[8]   = {64,32,16,8,16,32,64,79};       // units
constexpr int LS[8]   = {0,8,72,104,120,128,144,176};   // input span start unit
constexpr int LO[8]   = {8,72,104,120,128,144,176,240}; // output start unit
constexpr int LKP[8]  = {96,96,64,32,32,64,96,160};     // K padded to 32
constexpr int LKS[8]  = {3,3,2,1,1,2,3,5};              // K-steps (KP/32)
constexpr int LUP[8]  = {64,32,16,16,16,32,64,80};      // padded rows in weight table
constexpr int WOFF[8] = {0,6144,9216,10240,10752,11264,13312,19456};
constexpr int WTOTAL  = 32256;                           // bf16 elems in weight table

// 8-wave schedule: per wave up to 3 (layer, firstTile, numTiles) groups.
// MFMA per wave per step: 7/7/7/7/8/9/9/9 (sum 63); tiles 3/2/2/2/2/3/3/3 (sum 20).
// Each l7 (sigmoid) tile owned by a distinct wave.
constexpr int WNG[8]     = {3,2,2,2,2,2,3,1};
constexpr int WGL[8][3]  = {{7,3,4},{7,2,0},{7,5,0},{7,5,0},{7,6,0},{6,1,0},{6,1,0},{0,0,0}};
constexpr int WGT0[8][3] = {{0,0,0},{1,0,0},{2,0,0},{3,1,0},{4,0,0},{1,0,0},{3,1,0},{1,0,0}};
constexpr int WGNT[8][3] = {{1,1,1},{1,1,0},{1,1,0},{1,1,0},{1,1,0},{2,1,0},{1,1,1},{3,0,0}};

DEVFN unsigned short f2bf(float f) {           // RNE (setup paths only)
  unsigned int u = __builtin_bit_cast(unsigned int, f);
  return (unsigned short)((u + 0x7FFFu + ((u >> 16) & 1u)) >> 16);
}
// hot-path pack: round-half-away (u+0x8000) + single v_perm_b32.
DEVFN unsigned int pk_rna(float a, float b) {
  unsigned int ua = __builtin_bit_cast(unsigned int, a) + 0x8000u;
  unsigned int ub = __builtin_bit_cast(unsigned int, b) + 0x8000u;
  return __builtin_amdgcn_perm(ub, ua, 0x07060302u);  // [ub.b3 ub.b2 ua.b3 ua.b2]
}
// fast sigmoid: v_exp + v_rcp instead of precise-division sequence.
DEVFN float sigmoidf(float v) {
  return __builtin_amdgcn_rcpf(1.0f + __expf(-v));
}

// ---------------- weight prep: fp32 -> transposed, padded bf16 table in d_ws ----------------
__global__ void __launch_bounds__(256) prep_weights(
    const float* Wx0, const float* Wh0, const float* Wx1, const float* Wh1,
    const float* Wx2, const float* Wh2, const float* Wx3, const float* Wh3,
    const float* Wx4, const float* Wh4, const float* Wx5, const float* Wh5,
    const float* Wx6, const float* Wh6, const float* Wx7, const float* Wh7,
    unsigned short* __restrict__ wt)
{
  const float* wxp[8] = {Wx0,Wx1,Wx2,Wx3,Wx4,Wx5,Wx6,Wx7};
  const float* whp[8] = {Wh0,Wh1,Wh2,Wh3,Wh4,Wh5,Wh6,Wh7};
  int idx = blockIdx.x * 256 + threadIdx.x;
  if (idx >= WTOTAL) return;
#pragma unroll
  for (int l = 0; l < 8; ++l) {
    int sz = LUP[l] * LKP[l];
    if (idx >= WOFF[l] && idx < WOFF[l] + sz) {
      int local = idx - WOFF[l];
      int j = local / LKP[l];
      int k = local - j * LKP[l];
      float v = 0.f;
      if (j < LU[l]) {
        if (l == 0) {
          if (k == 0) v = Wx0[j];
          else if (k >= 8 && k < 72) v = Wh0[(k - 8) * 64 + j];
        } else {
          if (k < LD[l]) v = wxp[l][k * LU[l] + j];
          else if (k < LD[l] + LU[l]) v = whp[l][(k - LD[l]) * LU[l] + j];
        }
      }
      wt[idx] = f2bf(v);
    }
  }
}

// ---------------- per-wave preload: a-frags (weights) + bias frags into registers ----------------
template <int W>
DEVFN void preload(const unsigned short* __restrict__ wt,
                   const float* const (&bptr)[8], int lane,
                   bf16x8 (&af)[9], f32x4 (&bi)[3])
{
  const int m0 = lane & 15, quad = lane >> 4;
  int ai = 0, ti = 0;
#pragma unroll
  for (int g = 0; g < 3; ++g) {
    if (g >= WNG[W]) break;
    const int l = WGL[W][g], t0 = WGT0[W][g], nt = WGNT[W][g];
    const int ks = LKS[l], Kp = LKP[l], u = LU[l];
#pragma unroll
    for (int t = 0; t < 3; ++t) {
      if (t >= nt) continue;
      const int j = (t0 + t) * 16 + m0;  // a-frag row = output unit j
      const unsigned short* base = wt + WOFF[l] + j * Kp;
#pragma unroll
      for (int k = 0; k < 5; ++k) {
        if (k >= ks) continue;
        af[ai + t * ks + k] = *reinterpret_cast<const bf16x8*>(base + k * 32 + quad * 8);
      }
      const float* bp = bptr[l];
      f32x4 bv;
#pragma unroll
      for (int r = 0; r < 4; ++r) {
        int j2 = (t0 + t) * 16 + quad * 4 + r;  // C/D row = unit, col = batch
        bv[r] = (j2 < u) ? bp[j2] : 0.0f;
      }
      bi[ti + t] = bv;
    }
    ai += nt * ks; ti += nt;
  }
}

// ---------------- one wavefront step for wave W (rb/wb are STATIC shared arrays) ------------
template <int W>
DEVFN void step(int s, const unsigned short (&rb)[MWG][ROWU], unsigned short (&wb)[MWG][ROWU],
                const bf16x8 (&af)[9], const f32x4 (&bi)[3],
                const unsigned short (*xl)[80], float* __restrict__ out,
                int bb, int lane)
{
  const int m = lane & 15, quad = lane >> 4;
  int ai = 0, ti = 0;
#pragma unroll
  for (int g = 0; g < 3; ++g) {
    if (g >= WNG[W]) break;
    const int l = WGL[W][g], t0 = WGT0[W][g], nt = WGNT[W][g];
    const int ks = LKS[l], S = LS[l], O = LO[l], u = LU[l];
    if (s >= l && s <= l + TSEQ - 1) {
      f32x4 acc[3];
      // K loop; first MFMA consumes bias frag directly as C (no acc-init copies)
#pragma unroll
      for (int k = 0; k < 5; ++k) {
        if (k >= ks) break;
        bf16x8 bfv = *reinterpret_cast<const bf16x8*>(&rb[m][S + k * 32 + quad * 8]);
#pragma unroll
        for (int t = 0; t < 3; ++t)
          if (t < nt)
            acc[t] = __builtin_amdgcn_mfma_f32_16x16x32_bf16(
                af[ai + t * ks + k], bfv, (k == 0) ? bi[ti + t] : acc[t], 0, 0, 0);
      }
      // epilogue: activation + RNA pack + one ds_write_b64 per tile
#pragma unroll
      for (int t = 0; t < 3; ++t) {
        if (t >= nt) continue;
        const int jb = (t0 + t) * 16 + quad * 4;
        float v0 = acc[t][0], v1 = acc[t][1], v2 = acc[t][2], v3 = acc[t][3];
        if (l == 7) {
          v0 = sigmoidf(v0); v1 = sigmoidf(v1); v2 = sigmoidf(v2); v3 = sigmoidf(v3);
          if (s == NSTEP - 1) {  // t==78: final h -> global output (fp32)
            float* op = out + (size_t)(bb + m) * 79 + jb;
            if (jb + 0 < 79) op[0] = v0;
            if (jb + 1 < 79) op[1] = v1;
            if (jb + 2 < 79) op[2] = v2;
            if (jb + 3 < 79) op[3] = v3;
          } else {
            uint2 pk;
            pk.x = pk_rna(v0, v1);
            pk.y = pk_rna(v2, v3);
            *reinterpret_cast<uint2*>(&wb[m][O + jb]) = pk;  // j=79 -> pad unit 319 (zero weight)
          }
        } else {
          if (jb < u) {  // guards pad rows (l3 tile) from clobbering neighbor units
            v0 = fmaxf(v0, 0.f); v1 = fmaxf(v1, 0.f); v2 = fmaxf(v2, 0.f); v3 = fmaxf(v3, 0.f);
            uint2 pk;
            pk.x = pk_rna(v0, v1);
            pk.y = pk_rna(v2, v3);
            *reinterpret_cast<uint2*>(&wb[m][O + jb]) = pk;
          }
        }
      }
    }
    ai += nt * ks; ti += nt;
  }
  // wave 1 (light) extra duty: stage x_{s+1} from LDS x-cache into unit 0
  if constexpr (W == 1) {
    if (lane < MWG && s < TSEQ - 1) {
      wb[lane][0] = xl[lane][s + 1];
    }
  }
}

template <typename F>
DEVFN void dispatch(int wid, F&& f) {
  switch (wid) {
    case 0: f(std::integral_constant<int,0>{}); break;
    case 1: f(std::integral_constant<int,1>{}); break;
    case 2: f(std::integral_constant<int,2>{}); break;
    case 3: f(std::integral_constant<int,3>{}); break;
    case 4: f(std::integral_constant<int,4>{}); break;
    case 5: f(std::integral_constant<int,5>{}); break;
    case 6: f(std::integral_constant<int,6>{}); break;
    default: f(std::integral_constant<int,7>{}); break;
  }
}

// ---------------- main wavefront kernel ----------------
// 512 threads = 8 waves/block; 1024 blocks -> 4 blocks/CU -> 8 waves/SIMD.
// Per-wave duty halved vs R7 (<=9 MFMA, <=3 tiles) so the exposed
// barrier/dep-latency gap (~50% of step time at 4 waves/SIMD) is covered by TLP.
__global__ void __launch_bounds__(512)
__attribute__((amdgpu_waves_per_eu(8, 8)))
rnn_wavefront(
    const float* __restrict__ x, const unsigned short* __restrict__ wt,
    const float* b0, const float* b1, const float* b2, const float* b3,
    const float* b4, const float* b5, const float* b6, const float* b7,
    float* __restrict__ out)
{
  __shared__ __align__(16) unsigned short hb0[MWG][ROWU];
  __shared__ __align__(16) unsigned short hb1[MWG][ROWU];
  __shared__ __align__(4)  unsigned short xl[MWG][80];   // block's x rows, bf16
  const int tid = threadIdx.x, lane = tid & 63, wid = tid >> 6;
  const int bb = blockIdx.x * MWG;
  const float* bptr[8] = {b0, b1, b2, b3, b4, b5, b6, b7};

  // zero both h buffers (pad units must be 0; h0 = 0)
  {
    unsigned int* p0 = (unsigned int*)&hb0[0][0];
    unsigned int* p1 = (unsigned int*)&hb1[0][0];
    constexpr int NW = MWG * ROWU / 2;  // dwords per buffer
    for (int i = tid; i < NW; i += 512) { p0[i] = 0; p1[i] = 0; }
  }
  // preload x: block's rows are one contiguous span x[bb*79 .. (bb+MWG)*79)
  {
    const float* xb = x + (size_t)bb * TSEQ;
    for (int i = tid; i < MWG * TSEQ; i += 512) {
      int r = i / TSEQ, c = i - r * TSEQ;
      xl[r][c] = f2bf(xb[i]);
    }
  }
  __syncthreads();
  if (tid < MWG) hb0[tid][0] = xl[tid][0];  // x_0

  bf16x8 af[9];
  f32x4  bi[3];
  dispatch(wid, [&](auto Wc) { preload<Wc.value>(wt, bptr, lane, af, bi); });
  __syncthreads();

#pragma unroll 1
  for (int s = 0; s < NSTEP; s += 2) {
    dispatch(wid, [&](auto Wc) { step<Wc.value>(s,     hb0, hb1, af, bi, xl, out, bb, lane); });
    __syncthreads();
    dispatch(wid, [&](auto Wc) { step<Wc.value>(s + 1, hb1, hb0, af, bi, xl, out, bb, lane); });
    __syncthreads();
  }
}

extern "C" void kernel_launch(void* const* d_in, const int* in_sizes, int n_in,
                              void* d_out, int out_size, void* d_ws, size_t ws_size,
                              hipStream_t stream)
{
  const float* x = (const float*)d_in[0];
  const float* Wx[8]; const float* Wh[8]; const float* b[8];
  for (int i = 0; i < 8; ++i) {
    Wx[i] = (const float*)d_in[1 + 3 * i];
    Wh[i] = (const float*)d_in[2 + 3 * i];
    b[i]  = (const float*)d_in[3 + 3 * i];
  }
  unsigned short* wt = (unsigned short*)d_ws;

  prep_weights<<<(WTOTAL + 255) / 256, 256, 0, stream>>>(
      Wx[0], Wh[0], Wx[1], Wh[1], Wx[2], Wh[2], Wx[3], Wh[3],
      Wx[4], Wh[4], Wx[5], Wh[5], Wx[6], Wh[6], Wx[7], Wh[7], wt);

  rnn_wavefront<<<NBLK, 512, 0, stream>>>(
      x, wt, b[0], b[1], b[2], b[3], b[4], b[5], b[6], b[7], (float*)d_out);
}

// Round 9
// 238.708 us; speedup vs baseline: 1.5350x; 1.5350x over previous
//
#include <hip/hip_runtime.h>
#include <hip/hip_bf16.h>

#define DEVFN static __device__ __forceinline__

typedef short bf16x8 __attribute__((ext_vector_type(8)));
typedef float f32x4  __attribute__((ext_vector_type(4)));

// ---------------- problem constants ----------------
constexpr int TSEQ  = 79;
constexpr int NSTEP = TSEQ + 7;    // 86 wavefront steps (even -> unroll by 2)
constexpr int MWG   = 16;          // batch rows per workgroup
constexpr int ROWU  = 344;         // LDS row stride in bf16 (172 dwords)
constexpr int NBLK  = 16384 / MWG; // 1024 blocks = 4 blocks/CU

// per-layer tables. Unit map: x at unit 0; layer l h at [LO[l], LO[l]+LU[l]).
constexpr int LD[8]   = {1,64,32,16,8,16,32,64};        // input dim
constexpr int LU[8]   = {64,32,16,8,16,32,64,79};       // units
constexpr int LS[8]   = {0,8,72,104,120,128,144,176};   // input span start unit
constexpr int LO[8]   = {8,72,104,120,128,144,176,240}; // output start unit
constexpr int LKP[8]  = {96,96,64,32,32,64,96,160};     // K padded to 32
constexpr int LKS[8]  = {3,3,2,1,1,2,3,5};              // K-steps (KP/32)
constexpr int LUP[8]  = {64,32,16,16,16,32,64,80};      // padded rows in weight table
constexpr int WOFF[8] = {0,6144,9216,10240,10752,11264,13312,19456};
constexpr int WTOTAL  = 32256;                           // bf16 elems in weight table

// wave schedule (R7 balance, group order staggered so waves hit different LDS
// spans right after each barrier). MFMA per wave per step: 15/16/16/16.
constexpr int WNG[4]     = {1,2,4,2};
constexpr int WGL[4][4]  = {{7,0,0,0},{1,7,0,0},{2,3,4,0},{5,6,0,0}};
constexpr int WGT0[4][4] = {{0,0,0,0},{0,3,0,0},{0,0,0,0},{0,0,0,0}};
constexpr int WGNT[4][4] = {{3,0,0,0},{2,2,0,0},{1,1,1,4},{2,4,0,0}};

DEVFN unsigned short f2bf(float f) {           // RNE (setup paths only)
  unsigned int u = __builtin_bit_cast(unsigned int, f);
  return (unsigned short)((u + 0x7FFFu + ((u >> 16) & 1u)) >> 16);
}
// hot-path pack: round-half-away (u+0x8000) + single v_perm_b32.
DEVFN unsigned int pk_rna(float a, float b) {
  unsigned int ua = __builtin_bit_cast(unsigned int, a) + 0x8000u;
  unsigned int ub = __builtin_bit_cast(unsigned int, b) + 0x8000u;
  return __builtin_amdgcn_perm(ub, ua, 0x07060302u);  // [ub.b3 ub.b2 ua.b3 ua.b2]
}
// fast sigmoid: v_exp + v_rcp instead of precise-division sequence.
DEVFN float sigmoidf(float v) {
  return __builtin_amdgcn_rcpf(1.0f + __expf(-v));
}

// ---------------- weight prep: fp32 -> transposed, padded bf16 table in d_ws ----------------
__global__ void __launch_bounds__(256) prep_weights(
    const float* Wx0, const float* Wh0, const float* Wx1, const float* Wh1,
    const float* Wx2, const float* Wh2, const float* Wx3, const float* Wh3,
    const float* Wx4, const float* Wh4, const float* Wx5, const float* Wh5,
    const float* Wx6, const float* Wh6, const float* Wx7, const float* Wh7,
    unsigned short* __restrict__ wt)
{
  const float* wxp[8] = {Wx0,Wx1,Wx2,Wx3,Wx4,Wx5,Wx6,Wx7};
  const float* whp[8] = {Wh0,Wh1,Wh2,Wh3,Wh4,Wh5,Wh6,Wh7};
  int idx = blockIdx.x * 256 + threadIdx.x;
  if (idx >= WTOTAL) return;
#pragma unroll
  for (int l = 0; l < 8; ++l) {
    int sz = LUP[l] * LKP[l];
    if (idx >= WOFF[l] && idx < WOFF[l] + sz) {
      int local = idx - WOFF[l];
      int j = local / LKP[l];
      int k = local - j * LKP[l];
      float v = 0.f;
      if (j < LU[l]) {
        if (l == 0) {
          if (k == 0) v = Wx0[j];
          else if (k >= 8 && k < 72) v = Wh0[(k - 8) * 64 + j];
        } else {
          if (k < LD[l]) v = wxp[l][k * LU[l] + j];
          else if (k < LD[l] + LU[l]) v = whp[l][(k - LD[l]) * LU[l] + j];
        }
      }
      wt[idx] = f2bf(v);
    }
  }
}

// ---------------- per-wave preload: a-frags (weights) + bias frags into registers ----------------
template <int W>
DEVFN void preload(const unsigned short* __restrict__ wt,
                   const float* const (&bptr)[8], int lane,
                   bf16x8 (&af)[16], f32x4 (&bi)[7])
{
  const int m0 = lane & 15, quad = lane >> 4;
  int ai = 0, ti = 0;
#pragma unroll
  for (int g = 0; g < 4; ++g) {
    if (g >= WNG[W]) break;
    const int l = WGL[W][g], t0 = WGT0[W][g], nt = WGNT[W][g];
    const int ks = LKS[l], Kp = LKP[l], u = LU[l];
#pragma unroll
    for (int t = 0; t < 4; ++t) {
      if (t >= nt) continue;
      const int j = (t0 + t) * 16 + m0;  // a-frag row = output unit j
      const unsigned short* base = wt + WOFF[l] + j * Kp;
#pragma unroll
      for (int k = 0; k < 5; ++k) {
        if (k >= ks) continue;
        af[ai + t * ks + k] = *reinterpret_cast<const bf16x8*>(base + k * 32 + quad * 8);
      }
      const float* bp = bptr[l];
      f32x4 bv;
#pragma unroll
      for (int r = 0; r < 4; ++r) {
        int j2 = (t0 + t) * 16 + quad * 4 + r;  // C/D row = unit, col = batch
        bv[r] = (j2 < u) ? bp[j2] : 0.0f;
      }
      bi[ti + t] = bv;
    }
    ai += nt * ks; ti += nt;
  }
}

// ---------------- one wavefront step for wave W (rb/wb are STATIC shared arrays) ------------
template <int W>
DEVFN void step(int s, const unsigned short (&rb)[MWG][ROWU], unsigned short (&wb)[MWG][ROWU],
                const bf16x8 (&af)[16], const f32x4 (&bi)[7],
                const unsigned short (*xl)[80], float* __restrict__ out,
                int bb, int lane)
{
  const int m = lane & 15, quad = lane >> 4;
  int ai = 0, ti = 0;
#pragma unroll
  for (int g = 0; g < 4; ++g) {
    if (g >= WNG[W]) break;
    const int l = WGL[W][g], t0 = WGT0[W][g], nt = WGNT[W][g];
    const int ks = LKS[l], S = LS[l], O = LO[l], u = LU[l];
    if (s >= l && s <= l + TSEQ - 1) {
      f32x4 acc[4];
      // K loop; first MFMA consumes bias frag directly as C (no acc-init copies)
#pragma unroll
      for (int k = 0; k < 5; ++k) {
        if (k >= ks) break;
        bf16x8 bfv = *reinterpret_cast<const bf16x8*>(&rb[m][S + k * 32 + quad * 8]);
#pragma unroll
        for (int t = 0; t < 4; ++t)
          if (t < nt)
            acc[t] = __builtin_amdgcn_mfma_f32_16x16x32_bf16(
                af[ai + t * ks + k], bfv, (k == 0) ? bi[ti + t] : acc[t], 0, 0, 0);
      }
      // epilogue: activation + RNA pack + one ds_write_b64 per tile
#pragma unroll
      for (int t = 0; t < 4; ++t) {
        if (t >= nt) continue;
        const int jb = (t0 + t) * 16 + quad * 4;
        float v0 = acc[t][0], v1 = acc[t][1], v2 = acc[t][2], v3 = acc[t][3];
        if (l == 7) {
          v0 = sigmoidf(v0); v1 = sigmoidf(v1); v2 = sigmoidf(v2); v3 = sigmoidf(v3);
          if (s == NSTEP - 1) {  // t==78: final h -> global output (fp32)
            float* op = out + (size_t)(bb + m) * 79 + jb;
            if (jb + 0 < 79) op[0] = v0;
            if (jb + 1 < 79) op[1] = v1;
            if (jb + 2 < 79) op[2] = v2;
            if (jb + 3 < 79) op[3] = v3;
          } else {
            uint2 pk;
            pk.x = pk_rna(v0, v1);
            pk.y = pk_rna(v2, v3);
            *reinterpret_cast<uint2*>(&wb[m][O + jb]) = pk;  // j=79 -> pad unit 319 (zero weight)
          }
        } else {
          if (jb < u) {  // guards pad rows (l3 tile) from clobbering neighbor units
            v0 = fmaxf(v0, 0.f); v1 = fmaxf(v1, 0.f); v2 = fmaxf(v2, 0.f); v3 = fmaxf(v3, 0.f);
            uint2 pk;
            pk.x = pk_rna(v0, v1);
            pk.y = pk_rna(v2, v3);
            *reinterpret_cast<uint2*>(&wb[m][O + jb]) = pk;
          }
        }
      }
    }
    ai += nt * ks; ti += nt;
  }
  // wave 0 (lightest) extra duty: stage x_{s+1} from LDS x-cache into unit 0
  if constexpr (W == 0) {
    if (lane < MWG && s < TSEQ - 1) {
      wb[lane][0] = xl[lane][s + 1];
    }
  }
}

// ---------------- main wavefront kernel ----------------
// __launch_bounds__(256, 1): min 1 wave/EU -> allocator gets a wide VGPR budget and
// settles naturally (we only need 4 waves/SIMD from the 1024-block grid).
// R8 lesson: forcing 8 waves/EU pinned VGPR=32 and spilled 80 GB; never again.
__global__ void __launch_bounds__(256, 1)
rnn_wavefront(
    const float* __restrict__ x, const unsigned short* __restrict__ wt,
    const float* b0, const float* b1, const float* b2, const float* b3,
    const float* b4, const float* b5, const float* b6, const float* b7,
    float* __restrict__ out)
{
  __shared__ __align__(16) unsigned short hb0[MWG][ROWU];
  __shared__ __align__(16) unsigned short hb1[MWG][ROWU];
  __shared__ __align__(4)  unsigned short xl[MWG][80];   // block's x rows, bf16
  const int tid = threadIdx.x, lane = tid & 63, wid = tid >> 6;
  const int bb = blockIdx.x * MWG;
  const float* bptr[8] = {b0, b1, b2, b3, b4, b5, b6, b7};

  // zero both h buffers (pad units must be 0; h0 = 0)
  {
    unsigned int* p0 = (unsigned int*)&hb0[0][0];
    unsigned int* p1 = (unsigned int*)&hb1[0][0];
    constexpr int NW = MWG * ROWU / 2;  // dwords per buffer
    for (int i = tid; i < NW; i += 256) { p0[i] = 0; p1[i] = 0; }
  }
  // preload x: block's rows are one contiguous span x[bb*79 .. (bb+MWG)*79)
  {
    const float* xb = x + (size_t)bb * TSEQ;
    for (int i = tid; i < MWG * TSEQ; i += 256) {
      int r = i / TSEQ, c = i - r * TSEQ;
      xl[r][c] = f2bf(xb[i]);
    }
  }
  __syncthreads();
  if (tid < MWG) hb0[tid][0] = xl[tid][0];  // x_0

  bf16x8 af[16];
  f32x4  bi[7];
  if (wid == 0)      preload<0>(wt, bptr, lane, af, bi);
  else if (wid == 1) preload<1>(wt, bptr, lane, af, bi);
  else if (wid == 2) preload<2>(wt, bptr, lane, af, bi);
  else               preload<3>(wt, bptr, lane, af, bi);
  __syncthreads();

#pragma unroll 1
  for (int s = 0; s < NSTEP; s += 2) {
    // even step: read hb0, write hb1
    if (wid == 0)      step<0>(s, hb0, hb1, af, bi, xl, out, bb, lane);
    else if (wid == 1) step<1>(s, hb0, hb1, af, bi, xl, out, bb, lane);
    else if (wid == 2) step<2>(s, hb0, hb1, af, bi, xl, out, bb, lane);
    else               step<3>(s, hb0, hb1, af, bi, xl, out, bb, lane);
    __syncthreads();
    // odd step: read hb1, write hb0
    if (wid == 0)      step<0>(s + 1, hb1, hb0, af, bi, xl, out, bb, lane);
    else if (wid == 1) step<1>(s + 1, hb1, hb0, af, bi, xl, out, bb, lane);
    else if (wid == 2) step<2>(s + 1, hb1, hb0, af, bi, xl, out, bb, lane);
    else               step<3>(s + 1, hb1, hb0, af, bi, xl, out, bb, lane);
    __syncthreads();
  }
}

extern "C" void kernel_launch(void* const* d_in, const int* in_sizes, int n_in,
                              void* d_out, int out_size, void* d_ws, size_t ws_size,
                              hipStream_t stream)
{
  const float* x = (const float*)d_in[0];
  const float* Wx[8]; const float* Wh[8]; const float* b[8];
  for (int i = 0; i < 8; ++i) {
    Wx[i] = (const float*)d_in[1 + 3 * i];
    Wh[i] = (const float*)d_in[2 + 3 * i];
    b[i]  = (const float*)d_in[3 + 3 * i];
  }
  unsigned short* wt = (unsigned short*)d_ws;

  prep_weights<<<(WTOTAL + 255) / 256, 256, 0, stream>>>(
      Wx[0], Wh[0], Wx[1], Wh[1], Wx[2], Wh[2], Wx[3], Wh[3],
      Wx[4], Wh[4], Wx[5], Wh[5], Wx[6], Wh[6], Wx[7], Wh[7], wt);

  rnn_wavefront<<<NBLK, 256, 0, stream>>>(
      x, wt, b[0], b[1], b[2], b[3], b[4], b[5], b[6], b[7], (float*)d_out);
}

// Round 10
// 207.016 us; speedup vs baseline: 1.7700x; 1.1531x over previous
//
#include <hip/hip_runtime.h>
#include <hip/hip_bf16.h>

#define DEVFN static __device__ __forceinline__

typedef short bf16x8 __attribute__((ext_vector_type(8)));
typedef float f32x4  __attribute__((ext_vector_type(4)));

// ---------------- problem constants ----------------
constexpr int TSEQ  = 79;
constexpr int NSTEP = TSEQ + 7;    // 86 wavefront steps (even -> unroll by 2)
constexpr int MWG   = 16;          // batch rows per workgroup
constexpr int ROWU  = 344;         // LDS row stride in bf16 (172 dwords, %32==12 -> uniform banks)
constexpr int NBLK  = 16384 / MWG; // 1024 blocks = 4 blocks/CU

// per-layer tables. Unit map: x at unit 0; layer l h at [LO[l], LO[l]+LU[l]).
constexpr int LD[8]   = {1,64,32,16,8,16,32,64};        // input dim
constexpr int LU[8]   = {64,32,16,8,16,32,64,79};       // units
constexpr int LS[8]   = {0,8,72,104,120,128,144,176};   // input span start unit
constexpr int LO[8]   = {8,72,104,120,128,144,176,240}; // output start unit
constexpr int LKP[8]  = {96,96,64,32,32,64,96,160};     // K padded to 32
constexpr int LKS[8]  = {3,3,2,1,1,2,3,5};              // K-steps (KP/32)
constexpr int LUP[8]  = {64,32,16,16,16,32,64,80};      // padded rows in weight table
constexpr int WOFF[8] = {0,6144,9216,10240,10752,11264,13312,19456};
constexpr int WTOTAL  = 32256;                           // bf16 elems in weight table

// wave schedule (R4's balanced split). MFMA per wave per step: 15/16/16/16.
// R9 lesson: do NOT reorder groups or loosen launch bounds — both regressed codegen.
constexpr int WNG[4]     = {1,2,4,2};
constexpr int WGL[4][4]  = {{7,0,0,0},{7,1,0,0},{0,2,3,4},{6,5,0,0}};
constexpr int WGT0[4][4] = {{0,0,0,0},{3,0,0,0},{0,0,0,0},{0,0,0,0}};
constexpr int WGNT[4][4] = {{3,0,0,0},{2,2,0,0},{4,1,1,1},{4,2,0,0}};

DEVFN unsigned short f2bf(float f) {           // RNE (setup paths only)
  unsigned int u = __builtin_bit_cast(unsigned int, f);
  return (unsigned short)((u + 0x7FFFu + ((u >> 16) & 1u)) >> 16);
}
// hot-path pack: round-half-away (u+0x8000) + single v_perm_b32.
// result: low16 = bf16(a), high16 = bf16(b).
DEVFN unsigned int pk_rna(float a, float b) {
  unsigned int ua = __builtin_bit_cast(unsigned int, a) + 0x8000u;
  unsigned int ub = __builtin_bit_cast(unsigned int, b) + 0x8000u;
  return __builtin_amdgcn_perm(ub, ua, 0x07060302u);  // [ub.b3 ub.b2 ua.b3 ua.b2]
}
// fast sigmoid: v_exp + v_rcp (~1 ulp each) instead of the precise-division
// sequence (v_div_scale/fmas/fixup, ~14 VALU). Error << bf16 state noise.
DEVFN float sigmoidf(float v) {
  return __builtin_amdgcn_rcpf(1.0f + __expf(-v));
}

// ---------------- weight prep: fp32 -> transposed, padded bf16 table in d_ws ----------------
__global__ void __launch_bounds__(256) prep_weights(
    const float* Wx0, const float* Wh0, const float* Wx1, const float* Wh1,
    const float* Wx2, const float* Wh2, const float* Wx3, const float* Wh3,
    const float* Wx4, const float* Wh4, const float* Wx5, const float* Wh5,
    const float* Wx6, const float* Wh6, const float* Wx7, const float* Wh7,
    unsigned short* __restrict__ wt)
{
  const float* wxp[8] = {Wx0,Wx1,Wx2,Wx3,Wx4,Wx5,Wx6,Wx7};
  const float* whp[8] = {Wh0,Wh1,Wh2,Wh3,Wh4,Wh5,Wh6,Wh7};
  int idx = blockIdx.x * 256 + threadIdx.x;
  if (idx >= WTOTAL) return;
#pragma unroll
  for (int l = 0; l < 8; ++l) {
    int sz = LUP[l] * LKP[l];
    if (idx >= WOFF[l] && idx < WOFF[l] + sz) {
      int local = idx - WOFF[l];
      int j = local / LKP[l];
      int k = local - j * LKP[l];
      float v = 0.f;
      if (j < LU[l]) {
        if (l == 0) {
          if (k == 0) v = Wx0[j];
          else if (k >= 8 && k < 72) v = Wh0[(k - 8) * 64 + j];
        } else {
          if (k < LD[l]) v = wxp[l][k * LU[l] + j];
          else if (k < LD[l] + LU[l]) v = whp[l][(k - LD[l]) * LU[l] + j];
        }
      }
      wt[idx] = f2bf(v);
    }
  }
}

// ---------------- per-wave preload: a-frags (weights) + bias frags into registers ----------------
template <int W>
DEVFN void preload(const unsigned short* __restrict__ wt,
                   const float* const (&bptr)[8], int lane,
                   bf16x8 (&af)[16], f32x4 (&bi)[7])
{
  const int m0 = lane & 15, quad = lane >> 4;
  int ai = 0, ti = 0;
#pragma unroll
  for (int g = 0; g < 4; ++g) {
    if (g >= WNG[W]) break;
    const int l = WGL[W][g], t0 = WGT0[W][g], nt = WGNT[W][g];
    const int ks = LKS[l], Kp = LKP[l], u = LU[l];
#pragma unroll
    for (int t = 0; t < 4; ++t) {
      if (t >= nt) continue;
      const int j = (t0 + t) * 16 + m0;  // a-frag row = output unit j
      const unsigned short* base = wt + WOFF[l] + j * Kp;
#pragma unroll
      for (int k = 0; k < 5; ++k) {
        if (k >= ks) continue;
        af[ai + t * ks + k] = *reinterpret_cast<const bf16x8*>(base + k * 32 + quad * 8);
      }
      const float* bp = bptr[l];
      f32x4 bv;
#pragma unroll
      for (int r = 0; r < 4; ++r) {
        int j2 = (t0 + t) * 16 + quad * 4 + r;  // C/D row = unit, col = batch
        bv[r] = (j2 < u) ? bp[j2] : 0.0f;
      }
      bi[ti + t] = bv;
    }
    ai += nt * ks; ti += nt;
  }
}

// ---------------- one wavefront step for wave W (rb/wb are STATIC shared arrays) ------------
template <int W>
DEVFN void step(int s, const unsigned short (&rb)[MWG][ROWU], unsigned short (&wb)[MWG][ROWU],
                const bf16x8 (&af)[16], const f32x4 (&bi)[7],
                const unsigned short (*xl)[80], float* __restrict__ out,
                int bb, int lane)
{
  const int m = lane & 15, quad = lane >> 4;
  int ai = 0, ti = 0;
#pragma unroll
  for (int g = 0; g < 4; ++g) {
    if (g >= WNG[W]) break;
    const int l = WGL[W][g], t0 = WGT0[W][g], nt = WGNT[W][g];
    const int ks = LKS[l], S = LS[l], O = LO[l], u = LU[l];
    if (s >= l && s <= l + TSEQ - 1) {
      f32x4 acc[4];
      // K loop; first MFMA consumes bias frag directly as C (no acc-init copies)
#pragma unroll
      for (int k = 0; k < 5; ++k) {
        if (k >= ks) break;
        bf16x8 bfv = *reinterpret_cast<const bf16x8*>(&rb[m][S + k * 32 + quad * 8]);
#pragma unroll
        for (int t = 0; t < 4; ++t)
          if (t < nt)
            acc[t] = __builtin_amdgcn_mfma_f32_16x16x32_bf16(
                af[ai + t * ks + k], bfv, (k == 0) ? bi[ti + t] : acc[t], 0, 0, 0);
      }
      // epilogue: activation + RNA pack (3 VALU/pair) + one ds_write_b64 per tile
#pragma unroll
      for (int t = 0; t < 4; ++t) {
        if (t >= nt) continue;
        const int jb = (t0 + t) * 16 + quad * 4;
        float v0 = acc[t][0], v1 = acc[t][1], v2 = acc[t][2], v3 = acc[t][3];
        if (l == 7) {
          v0 = sigmoidf(v0); v1 = sigmoidf(v1); v2 = sigmoidf(v2); v3 = sigmoidf(v3);
          if (s == NSTEP - 1) {  // t==78: final h -> global output (fp32)
            float* op = out + (size_t)(bb + m) * 79 + jb;
            if (jb + 0 < 79) op[0] = v0;
            if (jb + 1 < 79) op[1] = v1;
            if (jb + 2 < 79) op[2] = v2;
            if (jb + 3 < 79) op[3] = v3;
          } else {
            uint2 pk;
            pk.x = pk_rna(v0, v1);
            pk.y = pk_rna(v2, v3);
            *reinterpret_cast<uint2*>(&wb[m][O + jb]) = pk;  // j=79 -> pad unit 319 (zero weight)
          }
        } else {
          if (jb < u) {  // guards pad rows (l3 tile) from clobbering neighbor units
            v0 = fmaxf(v0, 0.f); v1 = fmaxf(v1, 0.f); v2 = fmaxf(v2, 0.f); v3 = fmaxf(v3, 0.f);
            uint2 pk;
            pk.x = pk_rna(v0, v1);
            pk.y = pk_rna(v2, v3);
            *reinterpret_cast<uint2*>(&wb[m][O + jb]) = pk;
          }
        }
      }
    }
    ai += nt * ks; ti += nt;
  }
  // wave 0 (lightest) extra duty: stage x_{s+1} from LDS x-cache into unit 0
  if constexpr (W == 0) {
    if (lane < MWG && s < TSEQ - 1) {
      wb[lane][0] = xl[lane][s + 1];
    }
  }
}

// ---------------- main wavefront kernel ----------------
// EXACT R7 configuration — measured best (120.9 us). waves_per_eu(4,4) + the
// resulting 64-VGPR allocation is empirically the optimal codegen point:
// R5 (1 wave/EU) 270 us, R8 (8 waves/EU) 284 us, R9 ((256,1), 76 VGPR) 154 us.
__global__ void __launch_bounds__(256)
__attribute__((amdgpu_waves_per_eu(4, 4)))
__attribute__((amdgpu_num_vgpr(128)))
rnn_wavefront(
    const float* __restrict__ x, const unsigned short* __restrict__ wt,
    const float* b0, const float* b1, const float* b2, const float* b3,
    const float* b4, const float* b5, const float* b6, const float* b7,
    float* __restrict__ out)
{
  __shared__ __align__(16) unsigned short hb0[MWG][ROWU];
  __shared__ __align__(16) unsigned short hb1[MWG][ROWU];
  __shared__ __align__(4)  unsigned short xl[MWG][80];   // block's x rows, bf16
  const int tid = threadIdx.x, lane = tid & 63, wid = tid >> 6;
  const int bb = blockIdx.x * MWG;
  const float* bptr[8] = {b0, b1, b2, b3, b4, b5, b6, b7};

  // zero both h buffers (pad units must be 0; h0 = 0)
  {
    unsigned int* p0 = (unsigned int*)&hb0[0][0];
    unsigned int* p1 = (unsigned int*)&hb1[0][0];
    constexpr int NW = MWG * ROWU / 2;  // dwords per buffer
    for (int i = tid; i < NW; i += 256) { p0[i] = 0; p1[i] = 0; }
  }
  // preload x: block's rows are one contiguous span x[bb*79 .. (bb+MWG)*79)
  {
    const float* xb = x + (size_t)bb * TSEQ;
    for (int i = tid; i < MWG * TSEQ; i += 256) {
      int r = i / TSEQ, c = i - r * TSEQ;
      xl[r][c] = f2bf(xb[i]);
    }
  }
  __syncthreads();
  if (tid < MWG) hb0[tid][0] = xl[tid][0];  // x_0

  bf16x8 af[16];
  f32x4  bi[7];
  if (wid == 0)      preload<0>(wt, bptr, lane, af, bi);
  else if (wid == 1) preload<1>(wt, bptr, lane, af, bi);
  else if (wid == 2) preload<2>(wt, bptr, lane, af, bi);
  else               preload<3>(wt, bptr, lane, af, bi);
  __syncthreads();

#pragma unroll 1
  for (int s = 0; s < NSTEP; s += 2) {
    // even step: read hb0, write hb1
    if (wid == 0)      step<0>(s, hb0, hb1, af, bi, xl, out, bb, lane);
    else if (wid == 1) step<1>(s, hb0, hb1, af, bi, xl, out, bb, lane);
    else if (wid == 2) step<2>(s, hb0, hb1, af, bi, xl, out, bb, lane);
    else               step<3>(s, hb0, hb1, af, bi, xl, out, bb, lane);
    __syncthreads();
    // odd step: read hb1, write hb0
    if (wid == 0)      step<0>(s + 1, hb1, hb0, af, bi, xl, out, bb, lane);
    else if (wid == 1) step<1>(s + 1, hb1, hb0, af, bi, xl, out, bb, lane);
    else if (wid == 2) step<2>(s + 1, hb1, hb0, af, bi, xl, out, bb, lane);
    else               step<3>(s + 1, hb1, hb0, af, bi, xl, out, bb, lane);
    __syncthreads();
  }
}

extern "C" void kernel_launch(void* const* d_in, const int* in_sizes, int n_in,
                              void* d_out, int out_size, void* d_ws, size_t ws_size,
                              hipStream_t stream)
{
  const float* x = (const float*)d_in[0];
  const float* Wx[8]; const float* Wh[8]; const float* b[8];
  for (int i = 0; i < 8; ++i) {
    Wx[i] = (const float*)d_in[1 + 3 * i];
    Wh[i] = (const float*)d_in[2 + 3 * i];
    b[i]  = (const float*)d_in[3 + 3 * i];
  }
  unsigned short* wt = (unsigned short*)d_ws;

  prep_weights<<<(WTOTAL + 255) / 256, 256, 0, stream>>>(
      Wx[0], Wh[0], Wx[1], Wh[1], Wx[2], Wh[2], Wx[3], Wh[3],
      Wx[4], Wh[4], Wx[5], Wh[5], Wx[6], Wh[6], Wx[7], Wh[7], wt);

  rnn_wavefront<<<NBLK, 256, 0, stream>>>(
      x, wt, b[0], b[1], b[2], b[3], b[4], b[5], b[6], b[7], (float*)d_out);
}